// Round 9
// baseline (91.759 us; speedup 1.0000x reference)
//
#include <hip/hip_runtime.h>

using uint = unsigned int;
typedef unsigned short ushort_t;
typedef float f32x4 __attribute__((ext_vector_type(4)));
typedef short short8 __attribute__((ext_vector_type(8)));

#define B_ 4
#define C_ 256
#define T_ 4096
#define U_ 64

static __device__ __forceinline__ float bflo(uint w) { return __uint_as_float(w << 16); }
static __device__ __forceinline__ float bfhi(uint w) { return __uint_as_float(w & 0xffff0000u); }
static __device__ __forceinline__ uint f2bf(float f) {
    uint x = __float_as_uint(f);
    return (x + 0x7fffu + ((x >> 16) & 1u)) >> 16;
}

// ---------------------------------------------------------------------------
// Kernel 0: W [C][U] fp32 -> WT [3][U][C] bf16 (once; L2-resident afterwards)
// ---------------------------------------------------------------------------
__global__ __launch_bounds__(256) void wconv_kernel(
    const float* __restrict__ Wq, const float* __restrict__ Wk,
    const float* __restrict__ Wv, ushort_t* __restrict__ WT)
{
    const int m = blockIdx.x >> 3;                 // matrix 0..2
    const int q = blockIdx.x & 7;
    const float* W = (m == 0) ? Wq : (m == 1) ? Wk : Wv;
    int g  = q * 256 + threadIdx.x;                // 0..2047
    int u  = g >> 5;
    int c8 = (g & 31) << 3;
    short8 o;
#pragma unroll
    for (int j = 0; j < 8; ++j)
        o[j] = (short)f2bf(W[(size_t)(c8 + j) * U_ + u]);
    *(short8*)(WT + ((size_t)m * U_ + u) * C_ + c8) = o;
}

// ---------------------------------------------------------------------------
// Kernel 1: MFMA projections (512 blocks). bid&1==0 -> Q from y1; ==1 -> K,V
// from y2. V is written TRANSPOSED: Vt[b][u][t] (bf16) for attn's PV B-frags.
// ---------------------------------------------------------------------------
__global__ __launch_bounds__(256) void proj_kernel(
    const float* __restrict__ y1, const float* __restrict__ y2,
    const ushort_t* __restrict__ WT,
    ushort_t* __restrict__ Qb, ushort_t* __restrict__ Kb, ushort_t* __restrict__ Vt)
{
    __shared__ alignas(16) ushort_t wt[2][64][264];

    const int bid = blockIdx.x;
    const int tid = threadIdx.x;
    const int p   = bid & 1;
    const int bq2 = bid >> 1;
    const int b   = bq2 >> 6;
    const int t0  = (bq2 & 63) << 6;
    const int wid = tid >> 6, l = tid & 63;
    const int lm  = l & 15, lg = l >> 4;

    // ---- stage WT (bf16, b128 copies) ----
    {
        const ushort_t* s0 = WT + (size_t)(p == 0 ? 0 : 1) * (U_ * C_);
        const ushort_t* s1 = WT + (size_t)2 * (U_ * C_);
#pragma unroll
        for (int it = 0; it < 8; ++it) {
            int idx = it * 256 + tid;
            int u = idx >> 5, c8 = (idx & 31) << 3;
            *(short8*)&wt[0][u][c8] = *(const short8*)(s0 + u * C_ + c8);
            if (p)
                *(short8*)&wt[1][u][c8] = *(const short8*)(s1 + u * C_ + c8);
        }
    }
    __syncthreads();

    const float* ysrc = ((p == 0) ? y1 : y2) + (size_t)b * (C_ * T_);
    const float* yp   = ysrc + (size_t)(8 * lg) * T_ + (t0 + 16 * wid + lm);

    f32x4 acc0[4] = {};
    f32x4 acc1[4] = {};
#pragma unroll
    for (int ks = 0; ks < 8; ++ks) {
        float av[8];
#pragma unroll
        for (int j = 0; j < 8; ++j)
            av[j] = yp[(size_t)(32 * ks + j) * T_];
        short8 af;
#pragma unroll
        for (int j = 0; j < 8; ++j)
            af[j] = (short)f2bf(av[j]);
#pragma unroll
        for (int n = 0; n < 4; ++n) {
            short8 bq = *(const short8*)&wt[0][16 * n + lm][32 * ks + 8 * lg];
            acc0[n] = __builtin_amdgcn_mfma_f32_16x16x32_bf16(af, bq, acc0[n], 0, 0, 0);
            if (p) {
                short8 bv = *(const short8*)&wt[1][16 * n + lm][32 * ks + 8 * lg];
                acc1[n] = __builtin_amdgcn_mfma_f32_16x16x32_bf16(af, bv, acc1[n], 0, 0, 0);
            }
        }
    }

    // epilogue: C/D layout col=lane&15 (u), row=(lane>>4)*4+reg (t)
    ushort_t* O0 = p ? Kb : Qb;
#pragma unroll
    for (int n = 0; n < 4; ++n)
#pragma unroll
        for (int r = 0; r < 4; ++r) {
            int t = t0 + 16 * wid + 4 * lg + r;
            int u = 16 * n + lm;
            O0[((size_t)b * T_ + t) * U_ + u] = (ushort_t)f2bf(acc0[n][r]);
            if (p)
                Vt[((size_t)b * U_ + u) * T_ + t] = (ushort_t)f2bf(acc1[n][r]);
        }
}

// ---------------------------------------------------------------------------
// Kernel 2: MFMA banded attention. 1024 blocks x 256 thr (4 waves), 16 rows.
// S = Q.K^T via MFMA (frags straight from global), cross-wave softmax via
// LDS sums, P staged bf16 in LDS, PV via MFMA with pre-transposed V.
// Band + zero stores issued after last barrier -> drain under PV / tail.
// ---------------------------------------------------------------------------
__global__ __launch_bounds__(256, 3) void attn_kernel(
    const ushort_t* __restrict__ Qb, const ushort_t* __restrict__ Kb,
    const ushort_t* __restrict__ Vt, float* __restrict__ gout)
{
    __shared__ alignas(16) ushort_t vt[64][296];    // V^T window, 37.9 KB
    __shared__ alignas(16) ushort_t alds[16][296];  // P bf16, 9.5 KB
    __shared__ float sums[4][4][4];                 // [wave][lg][reg]

    const int bid = blockIdx.x;
    const int b   = bid >> 8;
    const int i0  = (bid & 255) << 4;
    const int tid = threadIdx.x;
    const int w   = tid >> 6, l = tid & 63;
    const int lm  = l & 15, lg = l >> 4;

    const int jb2    = max(0, i0 - 127) & ~7;       // 8-aligned window start
    const int jend   = min(T_, i0 + 144);
    const int width2 = jend - jb2;                  // mult of 8, <= 272
    const int NT     = (width2 + 15) >> 4;          // <= 17 j-tiles

    // ---- stage V^T window (zero-padded to 288 cols) ----
    {
        const int su = tid >> 2;                    // row u
        const int c0 = tid & 3;
        const ushort_t* vrow = Vt + ((size_t)b * U_ + su) * T_ + jb2;
#pragma unroll
        for (int k = 0; k < 9; ++k) {
            int c = c0 + 4 * k;                     // chunk 0..35
            short8 v = {};
            if (8 * c < width2)
                v = *(const short8*)(vrow + 8 * c);
            *(short8*)&vt[su][8 * c] = v;
        }
    }

    // ---- S phase: Q (global) x K^T (global) -> exp -> partial row sums ----
    const ushort_t* qrow = Qb + ((size_t)b * T_ + i0 + lm) * U_ + 8 * lg;
    const short8 aq0 = *(const short8*)(qrow);
    const short8 aq1 = *(const short8*)(qrow + 32);

    const int ivec = i0 + 4 * lg;                   // rows ivec+reg (D layout)
    f32x4 ev[5];
    f32x4 psum = {};
#pragma unroll
    for (int s = 0; s < 5; ++s) {
        const int jt = 4 * s + w;
        ev[s] = (f32x4)(0.f);
        if (jt < 18) {
            const int j    = jb2 + 16 * jt + lm;
            const int krow = min(j, T_ - 1);
            const ushort_t* kp = Kb + ((size_t)b * T_ + krow) * U_ + 8 * lg;
            short8 bk0 = *(const short8*)(kp);
            short8 bk1 = *(const short8*)(kp + 32);
            f32x4 acc = {};
            acc = __builtin_amdgcn_mfma_f32_16x16x32_bf16(aq0, bk0, acc, 0, 0, 0);
            acc = __builtin_amdgcn_mfma_f32_16x16x32_bf16(aq1, bk1, acc, 0, 0, 0);
#pragma unroll
            for (int r = 0; r < 4; ++r) {
                int i = ivec + r;
                bool valid = (j >= i - 127) && (j <= i + 128) && (j < T_);
                float e = valid ? __expf(acc[r] * 0.125f) : 0.f;
                ev[s][r] = e;
                psum[r] += e;
            }
        }
    }
    // reduce across the 16 lanes (lm) of each lg group
#pragma unroll
    for (int m = 1; m < 16; m <<= 1) {
#pragma unroll
        for (int r = 0; r < 4; ++r)
            psum[r] += __shfl_xor(psum[r], m, 64);
    }
    if (lm == 0)
        *(f32x4*)&sums[w][lg][0] = psum;
    __syncthreads();                                 // barrier A

    // ---- totals, normalize, stage P (bf16) into LDS ----
    f32x4 rtot = *(f32x4*)&sums[0][lg][0];
    rtot += *(f32x4*)&sums[1][lg][0];
    rtot += *(f32x4*)&sums[2][lg][0];
    rtot += *(f32x4*)&sums[3][lg][0];
    f32x4 rinv;
#pragma unroll
    for (int r = 0; r < 4; ++r)
        rinv[r] = __builtin_amdgcn_rcpf(rtot[r]);

    f32x4 av[5];
#pragma unroll
    for (int s = 0; s < 5; ++s) {
        const int jt = 4 * s + w;
        if (jt < 18) {
#pragma unroll
            for (int r = 0; r < 4; ++r) {
                float a = ev[s][r] * rinv[r];
                av[s][r] = a;
                alds[4 * lg + r][16 * jt + lm] = (ushort_t)f2bf(a);
            }
        }
    }
    __syncthreads();                                 // barrier B (lds ready)

    // ---- band stores + zero stores (fire-and-forget; drain under PV) ----
    float* aout = gout + (size_t)B_ * U_ * T_;
#pragma unroll
    for (int s = 0; s < 5; ++s) {
        const int jt = 4 * s + w;
        if (jt < 18) {
            const int j = jb2 + 16 * jt + lm;
#pragma unroll
            for (int r = 0; r < 4; ++r) {
                int i = ivec + r;
                if ((j >= i - 127) && (j <= i + 128) && (j < T_))
                    __builtin_nontemporal_store(av[s][r],
                        aout + ((size_t)b * T_ + i) * T_ + j);
            }
        }
    }
    {
        const f32x4 zz = (f32x4)(0.f);
#pragma unroll
        for (int rr = 0; rr < 4; ++rr) {
            const int i   = i0 + 4 * w + rr;
            const int jlo = max(0, i - 127);
            const int jhi = min(T_ - 1, i + 128);
            float* rowp = aout + ((size_t)b * T_ + i) * T_;
            f32x4* row4 = (f32x4*)rowp;
            int nleft4 = jlo >> 2;
            for (int k = l; k < nleft4; k += 64)
                __builtin_nontemporal_store(zz, row4 + k);
            int rem = jlo & 3;
            if (l < rem)
                __builtin_nontemporal_store(0.f, rowp + (jlo & ~3) + l);
            int js = jhi + 1;
            int ah = (4 - (js & 3)) & 3;
            if (l < ah && js + l < T_)
                __builtin_nontemporal_store(0.f, rowp + js + l);
            int js4 = (js + ah) >> 2;
            for (int k = js4 + l; k < T_ / 4; k += 64)
                __builtin_nontemporal_store(zz, row4 + k);
        }
    }

    // ---- PV via MFMA: out[r][u] = sum_j P[r][j] V[j][u], n-tile = wave ----
    f32x4 pacc = {};
#pragma unroll
    for (int kc = 0; kc < 9; ++kc) {
        short8 pa = *(const short8*)&alds[lm][8 * lg + 32 * kc];
        short8 pb = *(const short8*)&vt[16 * w + lm][8 * lg + 32 * kc];
        pacc = __builtin_amdgcn_mfma_f32_16x16x32_bf16(pa, pb, pacc, 0, 0, 0);
    }
    // D layout: row(=query r) = 4*lg+reg, col(=u within tile) = lm
#pragma unroll
    for (int r = 0; r < 4; ++r)
        gout[((size_t)b * U_ + 16 * w + lm) * T_ + i0 + 4 * lg + r] = pacc[r];
}

// ---------------------------------------------------------------------------
extern "C" void kernel_launch(void* const* d_in, const int* in_sizes, int n_in,
                              void* d_out, int out_size, void* d_ws, size_t ws_size,
                              hipStream_t stream)
{
    const float* y1 = (const float*)d_in[0];
    const float* y2 = (const float*)d_in[1];
    const float* Wq = (const float*)d_in[2];
    const float* Wk = (const float*)d_in[3];
    const float* Wv = (const float*)d_in[4];
    // d_in[5] = attention_width (== 256, compiled in)

    // workspace: Qb, Kb [B][T][64] bf16; Vt [B][64][T] bf16; WT [3][64][256]
    ushort_t* Qb = (ushort_t*)d_ws;
    ushort_t* Kb = Qb + (size_t)B_ * T_ * U_;
    ushort_t* Vt = Kb + (size_t)B_ * T_ * U_;
    ushort_t* WT = Vt + (size_t)B_ * T_ * U_;

    float* gout = (float*)d_out;

    wconv_kernel<<<24, 256, 0, stream>>>(Wq, Wk, Wv, WT);
    proj_kernel<<<512, 256, 0, stream>>>(y1, y2, WT, Qb, Kb, Vt);
    attn_kernel<<<1024, 256, 0, stream>>>(Qb, Kb, Vt, gout);
}

// Round 10
// 86.102 us; speedup vs baseline: 1.0657x; 1.0657x over previous
//
#include <hip/hip_runtime.h>

using uint = unsigned int;
typedef unsigned short ushort_t;
typedef float f32x4 __attribute__((ext_vector_type(4)));
typedef short short8 __attribute__((ext_vector_type(8)));

#define B_ 4
#define C_ 256
#define T_ 4096
#define U_ 64

static __device__ __forceinline__ float bflo(uint w) { return __uint_as_float(w << 16); }
static __device__ __forceinline__ float bfhi(uint w) { return __uint_as_float(w & 0xffff0000u); }
static __device__ __forceinline__ uint f2bf(float f) {
    uint x = __float_as_uint(f);
    return (x + 0x7fffu + ((x >> 16) & 1u)) >> 16;
}

// ---------------------------------------------------------------------------
// Kernel 1: MFMA projections (R3-proven). blockIdx.y==0 -> Q from y1;
// ==1 -> K,V from y2. Q,K row-major bf16 [B][T][64]; V TRANSPOSED Vt[B][64][T].
// ---------------------------------------------------------------------------
__global__ __launch_bounds__(256) void proj_kernel(
    const float* __restrict__ y1, const float* __restrict__ y2,
    const float* __restrict__ Wq, const float* __restrict__ Wk,
    const float* __restrict__ Wv,
    ushort_t* __restrict__ Qb, ushort_t* __restrict__ Kb, ushort_t* __restrict__ Vt)
{
    __shared__ alignas(16) ushort_t wt[2][64][264];

    const int p   = blockIdx.y;
    const int b   = blockIdx.x >> 6;
    const int t0  = (blockIdx.x & 63) << 6;
    const int tid = threadIdx.x;

    // ---- stage W^T (fp32 -> bf16) ----
    {
        const float* W0 = (p == 0) ? Wq : Wk;
#pragma unroll
        for (int k = 0; k < 64; ++k) {
            int idx = tid + 256 * k;          // idx = c*64 + u
            int c = idx >> 6, u = idx & 63;
            wt[0][u][c] = (ushort_t)f2bf(W0[idx]);
        }
        if (p == 1) {
#pragma unroll
            for (int k = 0; k < 64; ++k) {
                int idx = tid + 256 * k;
                int c = idx >> 6, u = idx & 63;
                wt[1][u][c] = (ushort_t)f2bf(Wv[idx]);
            }
        }
    }
    __syncthreads();

    const int wid = tid >> 6, l = tid & 63;
    const int lm = l & 15, lg = l >> 4;

    const float* ysrc = ((p == 0) ? y1 : y2) + (size_t)b * (C_ * T_);
    const float* yp   = ysrc + (size_t)(8 * lg) * T_ + (t0 + 16 * wid + lm);

    f32x4 acc0[4] = {};
    f32x4 acc1[4] = {};
#pragma unroll
    for (int ks = 0; ks < 8; ++ks) {
        float av[8];
#pragma unroll
        for (int j = 0; j < 8; ++j)
            av[j] = yp[(size_t)(32 * ks + j) * T_];
        short8 af;
#pragma unroll
        for (int j = 0; j < 8; ++j)
            af[j] = (short)f2bf(av[j]);
#pragma unroll
        for (int n = 0; n < 4; ++n) {
            short8 bq = *(const short8*)&wt[0][16 * n + lm][32 * ks + 8 * lg];
            acc0[n] = __builtin_amdgcn_mfma_f32_16x16x32_bf16(af, bq, acc0[n], 0, 0, 0);
            if (p) {
                short8 bv = *(const short8*)&wt[1][16 * n + lm][32 * ks + 8 * lg];
                acc1[n] = __builtin_amdgcn_mfma_f32_16x16x32_bf16(af, bv, acc1[n], 0, 0, 0);
            }
        }
    }

    // epilogue: C/D layout col=lane&15 (u), row=(lane>>4)*4+reg (t)
    ushort_t* O0 = p ? Kb : Qb;
#pragma unroll
    for (int n = 0; n < 4; ++n)
#pragma unroll
        for (int r = 0; r < 4; ++r) {
            int t = t0 + 16 * wid + 4 * lg + r;
            int u = 16 * n + lm;
            O0[((size_t)b * T_ + t) * U_ + u] = (ushort_t)f2bf(acc0[n][r]);
            if (p)
                Vt[((size_t)b * U_ + u) * T_ + t] = (ushort_t)f2bf(acc1[n][r]);
        }
}

// ---------------------------------------------------------------------------
// Kernel 2: full-MFMA banded attention. 512 blocks x 512 thr (8 waves),
// 32 rows/block, window 288 (swizzled LDS). S: 2 MFMA/j-tile; cross-wave
// softmax via LDS partials; PV: A=V^T, B=P -> coalesced out stores.
// All a-stores (band+zeros) issued AFTER the last barrier (no drain stalls).
// ---------------------------------------------------------------------------
__global__ __launch_bounds__(512) void attn_kernel(
    const ushort_t* __restrict__ Qb, const ushort_t* __restrict__ Kb,
    const ushort_t* __restrict__ Vt, float* __restrict__ gout)
{
    __shared__ alignas(16) uint     kw[288 * 32];     // K window, swizzled, 36.9 KB
    __shared__ alignas(16) ushort_t vt[64][296];      // V^T window, 37.9 KB
    __shared__ alignas(16) ushort_t alds[32][296];    // P bf16, 18.9 KB
    __shared__ alignas(16) uint     qlds[32][32];     // Q bf16x2, swizzled, 4 KB
    __shared__ float sums[8][20];                     // softmax partials

    const int bid = blockIdx.x;
    const int b   = bid >> 7;
    const int i0  = (bid & 127) << 5;
    const int tid = threadIdx.x;

    const int jb2    = max(0, i0 - 127) & ~7;         // 8-aligned window start
    const int jend   = min(T_, i0 + 160);
    const int width2 = jend - jb2;                    // always mult of 16
    const int NT     = width2 >> 4;                   // j-tiles (<=18)

    // ---- stage K window (uint4 chunks, XOR-swizzled) ----
    for (int idx = tid; idx < 2304; idx += 512) {
        int row = idx >> 3, q = idx & 7;
        int srow = min(jb2 + row, T_ - 1);
        uint4 v = ((const uint4*)(Kb + ((size_t)b * T_ + srow) * U_))[q];
        *(uint4*)(kw + row * 32 + ((4 * q) ^ ((row & 7) << 2))) = v;
    }
    // ---- stage V^T window (zero-padded) ----
    {
        const int u = tid >> 3, c0 = tid & 7;
        const ushort_t* vrow = Vt + ((size_t)b * U_ + u) * T_ + jb2;
#pragma unroll
        for (int k = 0; k < 5; ++k) {
            int c = c0 + 8 * k;
            if (c < 37) {
                short8 v = {};
                if (8 * c < width2)
                    v = *(const short8*)(vrow + 8 * c);
                *(short8*)&vt[u][8 * c] = v;
            }
        }
    }
    // ---- stage Q tile (bf16 packed, XOR-swizzled) ----
    if (tid < 256) {
        const int row = tid >> 3, q = tid & 7;
        uint4 v = ((const uint4*)(Qb + ((size_t)b * T_ + i0 + row) * U_))[q];
        *(uint4*)&qlds[row][(4 * q) ^ ((row & 7) << 2)] = v;
    }
    // ---- zero P ----
    {
        short8 z = {};
        short8* af = (short8*)&alds[0][0];
        for (int idx = tid; idx < 1184; idx += 512)
            af[idx] = z;
    }
    __syncthreads();

    const int w = tid >> 6, l = tid & 63;
    const int lm = l & 15, lg = l >> 4;
    const int qt = w & 1, jt0 = w >> 1;
    const int selq = (lm & 7) << 2;

    // ---- S phase: Q x K^T via MFMA, mask, exp, partial row sums ----
    const uint* qr = &qlds[16 * qt + lm][0];
    const short8 aq0 = *(const short8*)(qr + ((4 * lg) ^ selq));
    const short8 aq1 = *(const short8*)(qr + ((16 + 4 * lg) ^ selq));

    f32x4 ev[5];
    f32x4 psum = {};
#pragma unroll
    for (int s = 0; s < 5; ++s) ev[s] = (f32x4)(0.f);
#pragma unroll
    for (int s = 0; s < 5; ++s) {
        const int jt = 4 * s + jt0;
        if (jt < NT) {
            const int row = 16 * jt + lm;
            const uint* kr = kw + row * 32;
            short8 bk0 = *(const short8*)(kr + ((4 * lg) ^ selq));
            short8 bk1 = *(const short8*)(kr + ((16 + 4 * lg) ^ selq));
            f32x4 acc = {};
            acc = __builtin_amdgcn_mfma_f32_16x16x32_bf16(aq0, bk0, acc, 0, 0, 0);
            acc = __builtin_amdgcn_mfma_f32_16x16x32_bf16(aq1, bk1, acc, 0, 0, 0);
            const int j = jb2 + row;
#pragma unroll
            for (int r = 0; r < 4; ++r) {
                int i = i0 + 16 * qt + 4 * lg + r;
                bool val = (j >= i - 127) && (j <= i + 128);
                float e = val ? __expf(acc[r] * 0.125f) : 0.f;
                ev[s][r] = e;
                psum[r] += e;
            }
        }
    }
#pragma unroll
    for (int m = 1; m < 16; m <<= 1) {
#pragma unroll
        for (int r = 0; r < 4; ++r)
            psum[r] += __shfl_xor(psum[r], m, 64);
    }
    if (lm == 0)
        *(f32x4*)&sums[w][4 * lg] = psum;
    __syncthreads();                                   // barrier A

    // ---- totals + normalize + stage P ----
    f32x4 rtot = *(const f32x4*)&sums[qt][4 * lg];
    rtot += *(const f32x4*)&sums[qt + 2][4 * lg];
    rtot += *(const f32x4*)&sums[qt + 4][4 * lg];
    rtot += *(const f32x4*)&sums[qt + 6][4 * lg];
    f32x4 rinv;
#pragma unroll
    for (int r = 0; r < 4; ++r)
        rinv[r] = __builtin_amdgcn_rcpf(rtot[r]);

#pragma unroll
    for (int s = 0; s < 5; ++s) {
        const int jt = 4 * s + jt0;
        if (jt < NT) {
#pragma unroll
            for (int r = 0; r < 4; ++r) {
                float a = ev[s][r] * rinv[r];
                ev[s][r] = a;
                alds[16 * qt + 4 * lg + r][16 * jt + lm] = (ushort_t)f2bf(a);
            }
        }
    }
    __syncthreads();                                   // barrier B (last)

    float* aout = gout + (size_t)B_ * U_ * T_;

    // ---- band stores (fire-and-forget; nothing waits on vmcnt after) ----
#pragma unroll
    for (int s = 0; s < 5; ++s) {
        const int jt = 4 * s + jt0;
        if (jt < NT) {
            const int j = jb2 + 16 * jt + lm;
#pragma unroll
            for (int r = 0; r < 4; ++r) {
                int i = i0 + 16 * qt + 4 * lg + r;
                if ((j >= i - 127) && (j <= i + 128))
                    __builtin_nontemporal_store(ev[s][r],
                        aout + ((size_t)b * T_ + i) * T_ + j);
            }
        }
    }
    // ---- zero stores: out-of-band of this wave's 4 rows ----
    {
        const f32x4 zz = (f32x4)(0.f);
#pragma unroll
        for (int rr = 0; rr < 4; ++rr) {
            const int i   = i0 + 4 * w + rr;
            const int jlo = max(0, i - 127);
            const int jhi = min(T_ - 1, i + 128);
            float* rowp = aout + ((size_t)b * T_ + i) * T_;
            f32x4* row4 = (f32x4*)rowp;
            int nleft4 = jlo >> 2;
            for (int k = l; k < nleft4; k += 64)
                __builtin_nontemporal_store(zz, row4 + k);
            int rem = jlo & 3;
            if (l < rem)
                __builtin_nontemporal_store(0.f, rowp + (jlo & ~3) + l);
            int js = jhi + 1;
            int ah = (4 - (js & 3)) & 3;
            if (l < ah && js + l < T_)
                __builtin_nontemporal_store(0.f, rowp + js + l);
            int js4 = (js + ah) >> 2;
            for (int k = js4 + l; k < T_ / 4; k += 64)
                __builtin_nontemporal_store(zz, row4 + k);
        }
    }

    // ---- PV via MFMA: A=V^T, B=P -> D[u][i]; coalesced out stores ----
    {
        const int wu = w >> 1, qp = w & 1;
        f32x4 pacc = {};
#pragma unroll
        for (int kc = 0; kc < 9; ++kc) {
            short8 pa = *(const short8*)&vt[16 * wu + lm][8 * lg + 32 * kc];
            short8 pb = *(const short8*)&alds[16 * qp + lm][8 * lg + 32 * kc];
            pacc = __builtin_amdgcn_mfma_f32_16x16x32_bf16(pa, pb, pacc, 0, 0, 0);
        }
#pragma unroll
        for (int r = 0; r < 4; ++r)
            gout[((size_t)b * U_ + 16 * wu + 4 * lg + r) * T_ + i0 + 16 * qp + lm] = pacc[r];
    }
}

// ---------------------------------------------------------------------------
extern "C" void kernel_launch(void* const* d_in, const int* in_sizes, int n_in,
                              void* d_out, int out_size, void* d_ws, size_t ws_size,
                              hipStream_t stream)
{
    const float* y1 = (const float*)d_in[0];
    const float* y2 = (const float*)d_in[1];
    const float* Wq = (const float*)d_in[2];
    const float* Wk = (const float*)d_in[3];
    const float* Wv = (const float*)d_in[4];
    // d_in[5] = attention_width (== 256, compiled in)

    // workspace: Qb, Kb [B][T][64] bf16; Vt [B][64][T] bf16
    ushort_t* Qb = (ushort_t*)d_ws;
    ushort_t* Kb = Qb + (size_t)B_ * T_ * U_;
    ushort_t* Vt = Kb + (size_t)B_ * T_ * U_;

    float* gout = (float*)d_out;

    proj_kernel<<<dim3(B_ * (T_ / 64), 2), 256, 0, stream>>>(y1, y2, Wq, Wk, Wv, Qb, Kb, Vt);
    attn_kernel<<<512, 512, 0, stream>>>(Qb, Kb, Vt, gout);
}